// Round 6
// baseline (139.975 us; speedup 1.0000x reference)
//
#include <hip/hip_runtime.h>
#include <math.h>

#define NN 50000
#define RR 8
#define EE 100000
#define BB 16384
#define ET 800000
#define ENDV 0xFFFFFFFFu

typedef unsigned int uint;
typedef unsigned short ushort;
typedef __attribute__((ext_vector_type(4))) float f32x4;
typedef _Float16 f16x8 __attribute__((ext_vector_type(8)));

// U16: 8 planes of [32768 slots][128] fp16 (plane r = U_r)
// Wfrag: [slot(9)][plane hi/lo][nfg(8)][ks(4)][lane(64)][8 fp16]; slot 8 = self kernel

// =================== prep: edge linked-list + emb16 + W prepack (NO LDS) ===================
// grid 400 x 256. All blocks: edge pack. Blocks 0..390: emb16. 391..399: Wfrag.
__global__ __launch_bounds__(256) void prep(
    const float* __restrict__ emb, const float* __restrict__ rel_k, const float* __restrict__ self_k,
    const int* __restrict__ adj_rows, const int* __restrict__ adj_cols, const float* __restrict__ adj_vals,
    uint* __restrict__ head, uint2* __restrict__ epack,
    ushort* __restrict__ emb16, ushort* __restrict__ Wfrag)
{
    const int tid = threadIdx.x, bid = blockIdx.x;

    // ---- edge pack: head[n*8+r] chain; epack[e] = {col<<16 | val_fp16, next} ----
    {
        int g = bid * 256 + tid;                  // 102400 threads, 8 edges each
        #pragma unroll
        for (int ii = 0; ii < 8; ii++) {
            int e = g + ii * 102400;
            if (e < ET) {
                int r = e / EE;
                int row = adj_rows[e];
                ushort v16 = __builtin_bit_cast(ushort, (_Float16)adj_vals[e]);
                uint old = atomicExch(&head[row * 8 + r], (uint)e);
                epack[e] = make_uint2(((uint)adj_cols[e] << 16) | (uint)v16, old);
            }
        }
    }

    if (bid < 391) {
        // ---- emb -> fp16, rows [bid*128, bid*128+128) ----
        #pragma unroll
        for (int i = 0; i < 16; i++) {
            int c = i * 256 + tid;
            int row = bid * 128 + (c >> 5);
            if (row < NN) {
                int k4 = (c & 31) * 4;
                float4 v = *(const float4*)(emb + (size_t)row * 128 + k4);
                _Float16 h4[4] = {(_Float16)v.x, (_Float16)v.y, (_Float16)v.z, (_Float16)v.w};
                *(ulonglong1*)(emb16 + (size_t)row * 128 + k4) = *(ulonglong1*)h4;
            }
        }
    } else {
        // ---- W prepack (hi/lo fragment layout), LDS-free ----
        int r = bid - 391;                        // 0..8 (8 = self)
        const float* src = (r < RR) ? rel_k + (size_t)r * 128 * 128 : self_k;
        #pragma unroll
        for (int q = 0; q < 8; q++) {
            int ls = q * 256 + tid;
            int nfg = ls >> 8, ks = (ls >> 6) & 3, lane = ls & 63;
            int n = nfg * 16 + (lane & 15);
            int k0 = ks * 32 + (lane >> 4) * 8;
            f16x8 hi, lo;
            #pragma unroll
            for (int j = 0; j < 8; j++) {
                float x = src[(size_t)(k0 + j) * 128 + n];   // 16 lanes -> 64B segment
                _Float16 h = (_Float16)x;
                hi[j] = h;
                lo[j] = (_Float16)(x - (float)h);
            }
            size_t bo = (size_t)(r * 2) * 16384 + (size_t)(nfg * 4 + ks) * 512 + (size_t)lane * 8;
            *(f16x8*)(Wfrag + bo)         = hi;
            *(f16x8*)(Wfrag + 16384 + bo) = lo;
        }
    }
}

// =================== gatherU: one 16-lane group per (slot, r); no barriers, no cap ===================
// grid 16384 x 256: bid>>11 = r; 16 consecutive slots per block -> coalesced U writes.
__global__ __launch_bounds__(256, 8) void gatherU(
    const int* __restrict__ head_idx, const int* __restrict__ tail_idx,
    const uint* __restrict__ head, const uint2* __restrict__ epack,
    const ushort* __restrict__ emb16, ushort* __restrict__ U16)
{
    const int tid = threadIdx.x, bid = blockIdx.x;
    const int g16 = tid >> 4, l16 = tid & 15;
    const int r = bid >> 11;
    const int slot = (bid & 2047) * 16 + g16;
    int n = (slot < BB) ? head_idx[slot] : tail_idx[slot - BB];
    uint e = head[n * 8 + r];
    f16x8 uu = {};
    if (e != ENDV) {                              // 13.5% of chains are empty: skip all loads
        float a[8] = {0.f,0.f,0.f,0.f,0.f,0.f,0.f,0.f};
        do {
            uint2 p = epack[e];                   // 8B broadcast across group
            float v = (float)__builtin_bit_cast(_Float16, (ushort)(p.x & 0xFFFFu));
            uint col = p.x >> 16;
            f16x8 em = *(const f16x8*)(emb16 + (size_t)col * 128 + l16 * 8);
            #pragma unroll
            for (int q = 0; q < 8; q++) a[q] = fmaf(v, (float)em[q], a[q]);
            e = p.y;
        } while (e != ENDV);
        #pragma unroll
        for (int q = 0; q < 8; q++) uu[q] = (_Float16)a[q];
    }
    *(f16x8*)(U16 + ((size_t)r * 32768 + slot) * 128 + l16 * 8) = uu;
}

// =================== gemm: out = sigmoid(self_fp32 @ Wself + sum_r U_r @ W_r) ===================
// grid 512 x 256. Tile 64 rows x 128 cols. Double-buffered swizzled LDS (T2/T14).
__global__ __launch_bounds__(256) void gemm(
    const float* __restrict__ head_e, const float* __restrict__ tail_e,
    const ushort* __restrict__ U16, const ushort* __restrict__ Wfrag,
    float* __restrict__ out)
{
    __shared__ char sA[2][16384];
    const int tid = threadIdx.x, bid = blockIdx.x;
    const int w = tid >> 6, l = tid & 63;
    const int lr = l & 15, kq = l >> 4;
    const int m0 = (w >> 1) * 32;                 // 2x2 wave grid
    const int nfg0 = (w & 1) * 4;

    f32x4 acc[2][4];
    #pragma unroll
    for (int a = 0; a < 2; a++)
        #pragma unroll
        for (int b = 0; b < 4; b++) acc[a][b] = (f32x4){0.f, 0.f, 0.f, 0.f};

    // ---- stage self rows: fp32 -> hi (sA[0]) / lo (sA[1]), swizzled ----
    const float* S = (bid < 256) ? head_e + (size_t)bid * 64 * 128
                                 : tail_e + (size_t)(bid - 256) * 64 * 128;
    #pragma unroll
    for (int i = 0; i < 4; i++) {
        int c = i * 256 + tid;                    // 1024 chunks (64 rows x 16 chunks of 8)
        int row = c >> 4;
        int k8 = (c & 15) * 8;
        float4 v0 = *(const float4*)(S + (size_t)row * 128 + k8);
        float4 v1 = *(const float4*)(S + (size_t)row * 128 + k8 + 4);
        float xs[8] = {v0.x, v0.y, v0.z, v0.w, v1.x, v1.y, v1.z, v1.w};
        f16x8 h, lo;
        #pragma unroll
        for (int j = 0; j < 8; j++) {
            _Float16 hh = (_Float16)xs[j];
            h[j] = hh;
            lo[j] = (_Float16)(xs[j] - (float)hh);
        }
        int off = row * 256 + ((k8 * 2) ^ ((row & 7) << 4));
        *(f16x8*)(sA[0] + off) = h;
        *(f16x8*)(sA[1] + off) = lo;
    }
    __syncthreads();

    float4 pf0, pf1, pf2, pf3;
    const char* Ub = (const char*)U16 + (size_t)bid * 64 * 256;

    #define STAGE(r) {                                                          \
        const char* gp = Ub + (size_t)(r) * 32768 * 256;                        \
        pf0 = *(const float4*)(gp + (0 * 256 + tid) * 16);                      \
        pf1 = *(const float4*)(gp + (1 * 256 + tid) * 16);                      \
        pf2 = *(const float4*)(gp + (2 * 256 + tid) * 16);                      \
        pf3 = *(const float4*)(gp + (3 * 256 + tid) * 16);                      \
    }
    #define WRITE(buf) {                                                        \
        _Pragma("unroll")                                                       \
        for (int i = 0; i < 4; i++) {                                           \
            int c = i * 256 + tid;                                              \
            int row = c >> 4, cc = c & 15;                                      \
            int off = row * 256 + ((cc * 16) ^ ((row & 7) << 4));               \
            *(float4*)(sA[buf] + off) = (i==0)?pf0:(i==1)?pf1:(i==2)?pf2:pf3;   \
        }                                                                       \
    }

    // ---- self superblock: 3-term (Ahi*Whi + Ahi*Wlo + Alo*Whi), W slot 8 ----
    STAGE(0);                                     // prefetch U0 under self MFMA
    {
        const ushort* Wb = Wfrag + (size_t)(8 * 2) * 16384;
        #pragma unroll
        for (int ks = 0; ks < 4; ks++) {
            int kb = ks * 64 + kq * 16;
            f16x8 ah[2], al[2], bh[4], bl[4];
            #pragma unroll
            for (int mf = 0; mf < 2; mf++) {
                int row = m0 + mf * 16 + lr;
                int off = row * 256 + (kb ^ ((row & 7) << 4));
                ah[mf] = *(const f16x8*)(sA[0] + off);
                al[mf] = *(const f16x8*)(sA[1] + off);
            }
            #pragma unroll
            for (int nf = 0; nf < 4; nf++) {
                size_t bo = (size_t)(((nfg0 + nf) * 4 + ks) * 64 + l) * 8;
                bh[nf] = *(const f16x8*)(Wb + bo);
                bl[nf] = *(const f16x8*)(Wb + 16384 + bo);
            }
            #pragma unroll
            for (int mf = 0; mf < 2; mf++)
                #pragma unroll
                for (int nf = 0; nf < 4; nf++) {
                    acc[mf][nf] = __builtin_amdgcn_mfma_f32_16x16x32_f16(ah[mf], bh[nf], acc[mf][nf], 0, 0, 0);
                    acc[mf][nf] = __builtin_amdgcn_mfma_f32_16x16x32_f16(ah[mf], bl[nf], acc[mf][nf], 0, 0, 0);
                    acc[mf][nf] = __builtin_amdgcn_mfma_f32_16x16x32_f16(al[mf], bh[nf], acc[mf][nf], 0, 0, 0);
                }
        }
    }
    __syncthreads();
    WRITE(0);
    __syncthreads();

    // ---- 8 U superblocks: 2-term (U*Whi + U*Wlo) ----
    for (int r = 0; r < RR; r++) {
        if (r < 7) STAGE(r + 1);
        const ushort* Wb = Wfrag + (size_t)(r * 2) * 16384;
        const char* bufp = sA[r & 1];
        #pragma unroll
        for (int ks = 0; ks < 4; ks++) {
            int kb = ks * 64 + kq * 16;
            f16x8 av[2], bh[4], bl[4];
            #pragma unroll
            for (int mf = 0; mf < 2; mf++) {
                int row = m0 + mf * 16 + lr;
                av[mf] = *(const f16x8*)(bufp + row * 256 + (kb ^ ((row & 7) << 4)));
            }
            #pragma unroll
            for (int nf = 0; nf < 4; nf++) {
                size_t bo = (size_t)(((nfg0 + nf) * 4 + ks) * 64 + l) * 8;
                bh[nf] = *(const f16x8*)(Wb + bo);
                bl[nf] = *(const f16x8*)(Wb + 16384 + bo);
            }
            #pragma unroll
            for (int mf = 0; mf < 2; mf++)
                #pragma unroll
                for (int nf = 0; nf < 4; nf++) {
                    acc[mf][nf] = __builtin_amdgcn_mfma_f32_16x16x32_f16(av[mf], bh[nf], acc[mf][nf], 0, 0, 0);
                    acc[mf][nf] = __builtin_amdgcn_mfma_f32_16x16x32_f16(av[mf], bl[nf], acc[mf][nf], 0, 0, 0);
                }
        }
        __syncthreads();
        if (r < 7) { WRITE((r + 1) & 1); __syncthreads(); }
    }

    // ---- epilogue: sigmoid + store (D: col = nf*16+lr, row = kq*4+j) ----
    #pragma unroll
    for (int mf = 0; mf < 2; mf++)
        #pragma unroll
        for (int j = 0; j < 4; j++) {
            int lrow = m0 + mf * 16 + kq * 4 + j;
            size_t slot = (size_t)bid * 64 + lrow;
            #pragma unroll
            for (int nf = 0; nf < 4; nf++) {
                int col = (w & 1) * 64 + nf * 16 + lr;
                float x = acc[mf][nf][j];
                out[slot * 128 + col] = 1.f / (1.f + __expf(-x));
            }
        }
    #undef STAGE
    #undef WRITE
}

extern "C" void kernel_launch(void* const* d_in, const int* in_sizes, int n_in,
                              void* d_out, int out_size, void* d_ws, size_t ws_size,
                              hipStream_t stream)
{
    const float* embeddings = (const float*)d_in[0];
    const int*   head_idx   = (const int*)d_in[1];
    const float* head_e     = (const float*)d_in[2];
    const int*   tail_idx   = (const int*)d_in[3];
    const float* tail_e     = (const float*)d_in[4];
    const int*   adj_rows   = (const int*)d_in[5];
    const int*   adj_cols   = (const int*)d_in[6];
    const float* adj_vals   = (const float*)d_in[7];
    const float* rel_k      = (const float*)d_in[8];
    const float* self_k     = (const float*)d_in[9];
    float* out = (float*)d_out;

    // workspace layout (~88.5 MB)
    char* ws = (char*)d_ws;
    uint*   head  = (uint*)ws;                        //  1,600,000 B
    ushort* Wfrag = (ushort*)(ws + 1600512);          //    589,824 B
    ushort* emb16 = (ushort*)(ws + 2190336);          // 12,800,000 B
    uint2*  epack = (uint2*)(ws + 14990336);          //  6,400,000 B
    ushort* U16   = (ushort*)(ws + 21390336);         // 67,108,864 B (8 planes x 32768 x 128)

    hipMemsetAsync(head, 0xFF, (size_t)NN * 8 * 4, stream);

    prep<<<400, 256, 0, stream>>>(embeddings, rel_k, self_k,
                                  adj_rows, adj_cols, adj_vals,
                                  head, epack, emb16, Wfrag);

    gatherU<<<16384, 256, 0, stream>>>(head_idx, tail_idx, head, epack, emb16, U16);

    gemm<<<512, 256, 0, stream>>>(head_e, tail_e, U16, Wfrag, out);
}

// Round 8
// 121.349 us; speedup vs baseline: 1.1535x; 1.1535x over previous
//
#include <hip/hip_runtime.h>
#include <math.h>

#define NN 50000
#define RR 8
#define EE 100000
#define BB 16384
#define ET 800000
#define ENDV 0xFFFFFFFFu

typedef unsigned int uint;
typedef unsigned short ushort;
typedef __attribute__((ext_vector_type(4))) float f32x4;
typedef _Float16 f16x8 __attribute__((ext_vector_type(8)));

// head: uint2 per (node, r): two parity sub-chain heads. epack[e] = {col<<16|val_fp16, next}
// U16: 8 planes of [32768 slots][128] fp16. Wfrag: [slot(9)][hi/lo][nfg(8)][ks(4)][lane(64)][8 f16]

// =================== prep: parity-split edge chains + emb16 + W prepack ===================
// grid 800 x 256. All blocks edge-pack (4 edges/thread). 0..390 emb16; 391..399 Wfrag.
__global__ __launch_bounds__(256) void prep(
    const float* __restrict__ emb, const float* __restrict__ rel_k, const float* __restrict__ self_k,
    const int* __restrict__ adj_rows, const int* __restrict__ adj_cols, const float* __restrict__ adj_vals,
    uint* __restrict__ head, uint2* __restrict__ epack,
    ushort* __restrict__ emb16, ushort* __restrict__ Wfrag)
{
    const int tid = threadIdx.x, bid = blockIdx.x;

    // ---- edge pack: 800K atomicExch into parity-split heads; coalesced 8B payload ----
    {
        int g = bid * 256 + tid;                  // 204800 threads, 4 edges each
        #pragma unroll
        for (int ii = 0; ii < 4; ii++) {
            int e = g + ii * 204800;
            if (e < ET) {
                int r = e / EE;
                int row = adj_rows[e];
                ushort v16 = __builtin_bit_cast(ushort, (_Float16)adj_vals[e]);
                uint old = atomicExch(&head[((size_t)row * 8 + r) * 2 + (e & 1)], (uint)e);
                epack[e] = make_uint2(((uint)adj_cols[e] << 16) | (uint)v16, old);
            }
        }
    }

    if (bid < 391) {
        // ---- emb -> fp16, rows [bid*128, bid*128+128) ----
        #pragma unroll
        for (int i = 0; i < 16; i++) {
            int c = i * 256 + tid;
            int row = bid * 128 + (c >> 5);
            if (row < NN) {
                int k4 = (c & 31) * 4;
                float4 v = *(const float4*)(emb + (size_t)row * 128 + k4);
                _Float16 h4[4] = {(_Float16)v.x, (_Float16)v.y, (_Float16)v.z, (_Float16)v.w};
                *(ulonglong1*)(emb16 + (size_t)row * 128 + k4) = *(ulonglong1*)h4;
            }
        }
    } else if (bid < 400) {
        // ---- W prepack (hi/lo fragment layout), LDS-free ----
        int r = bid - 391;                        // 0..8 (8 = self)
        const float* src = (r < RR) ? rel_k + (size_t)r * 128 * 128 : self_k;
        #pragma unroll
        for (int q = 0; q < 8; q++) {
            int ls = q * 256 + tid;
            int nfg = ls >> 8, ks = (ls >> 6) & 3, lane = ls & 63;
            int n = nfg * 16 + (lane & 15);
            int k0 = ks * 32 + (lane >> 4) * 8;
            f16x8 hi, lo;
            #pragma unroll
            for (int j = 0; j < 8; j++) {
                float x = src[(size_t)(k0 + j) * 128 + n];
                _Float16 h = (_Float16)x;
                hi[j] = h;
                lo[j] = (_Float16)(x - (float)h);
            }
            size_t bo = (size_t)(r * 2) * 16384 + (size_t)(nfg * 4 + ks) * 512 + (size_t)lane * 8;
            *(f16x8*)(Wfrag + bo)         = hi;
            *(f16x8*)(Wfrag + 16384 + bo) = lo;
        }
    }
}

// =================== gatherU: two parity chains walked concurrently per 16-lane group ===================
// grid 16384 x 256: bid>>11 = r; 16 consecutive slots per block.
__global__ __launch_bounds__(256, 8) void gatherU(
    const int* __restrict__ head_idx, const int* __restrict__ tail_idx,
    const uint* __restrict__ head, const uint2* __restrict__ epack,
    const ushort* __restrict__ emb16, ushort* __restrict__ U16)
{
    const int tid = threadIdx.x, bid = blockIdx.x;
    const int g16 = tid >> 4, l16 = tid & 15;
    const int r = bid >> 11;
    const int slot = (bid & 2047) * 16 + g16;
    int n = (slot < BB) ? head_idx[slot] : tail_idx[slot - BB];
    uint2 h2 = *(const uint2*)(head + ((size_t)n * 8 + r) * 2);
    uint e0 = h2.x, e1 = h2.y;
    float a[8] = {0.f,0.f,0.f,0.f,0.f,0.f,0.f,0.f};
    while (e0 != ENDV || e1 != ENDV) {
        bool b0 = (e0 != ENDV), b1 = (e1 != ENDV);
        uint2 p0, p1;
        if (b0) p0 = epack[e0];                   // the two hop loads overlap (independent)
        if (b1) p1 = epack[e1];
        f16x8 em0, em1;
        if (b0) em0 = *(const f16x8*)(emb16 + (size_t)(p0.x >> 16) * 128 + l16 * 8);
        if (b1) em1 = *(const f16x8*)(emb16 + (size_t)(p1.x >> 16) * 128 + l16 * 8);
        if (b0) {
            float v = (float)__builtin_bit_cast(_Float16, (ushort)(p0.x & 0xFFFFu));
            #pragma unroll
            for (int q = 0; q < 8; q++) a[q] = fmaf(v, (float)em0[q], a[q]);
            e0 = p0.y;
        }
        if (b1) {
            float v = (float)__builtin_bit_cast(_Float16, (ushort)(p1.x & 0xFFFFu));
            #pragma unroll
            for (int q = 0; q < 8; q++) a[q] = fmaf(v, (float)em1[q], a[q]);
            e1 = p1.y;
        }
    }
    f16x8 uu;
    #pragma unroll
    for (int q = 0; q < 8; q++) uu[q] = (_Float16)a[q];
    *(f16x8*)(U16 + ((size_t)r * 32768 + slot) * 128 + l16 * 8) = uu;
}

// =================== gemm: out = sigmoid(self_fp32 @ Wself + sum_r U_r @ W_r) ===================
// grid 512 x 256. Tile 64 rows x 128 cols; wave = 64r x 32c (mf=4, nfg=2).
// 3-buffer LDS rotation, ONE sync per superblock.
// Rotation invariant: U_r is READ from buf (r+2)%3, so U_{r+1} staged at iter r
// must be WRITTEN to buf ((r+1)+2)%3 == r%3.  (Round-7 bug: wrote (r+1)%3.)
__global__ __launch_bounds__(256) void gemm(
    const float* __restrict__ head_e, const float* __restrict__ tail_e,
    const ushort* __restrict__ U16, const ushort* __restrict__ Wfrag,
    float* __restrict__ out)
{
    __shared__ char sA[3][16384];
    const int tid = threadIdx.x, bid = blockIdx.x;
    const int w = tid >> 6, l = tid & 63;
    const int lr = l & 15, kq = l >> 4;
    const int nfg0 = w * 2;                       // wave covers cols [w*32, w*32+32)

    f32x4 acc[4][2];
    #pragma unroll
    for (int a = 0; a < 4; a++)
        #pragma unroll
        for (int b = 0; b < 2; b++) acc[a][b] = (f32x4){0.f, 0.f, 0.f, 0.f};

    // ---- stage self rows (64): fp32 -> hi (sA[0]) / lo (sA[1]), swizzled ----
    const float* S = (bid < 256) ? head_e + (size_t)bid * 64 * 128
                                 : tail_e + (size_t)(bid - 256) * 64 * 128;
    #pragma unroll
    for (int i = 0; i < 4; i++) {
        int c = i * 256 + tid;                    // 1024 chunks (64 rows x 16 x 8 f16)
        int row = c >> 4;
        int k8 = (c & 15) * 8;
        float4 v0 = *(const float4*)(S + (size_t)row * 128 + k8);
        float4 v1 = *(const float4*)(S + (size_t)row * 128 + k8 + 4);
        float xs[8] = {v0.x, v0.y, v0.z, v0.w, v1.x, v1.y, v1.z, v1.w};
        f16x8 h, lo;
        #pragma unroll
        for (int j = 0; j < 8; j++) {
            _Float16 hh = (_Float16)xs[j];
            h[j] = hh;
            lo[j] = (_Float16)(xs[j] - (float)hh);
        }
        int off = row * 256 + ((k8 * 2) ^ ((row & 7) << 4));
        *(f16x8*)(sA[0] + off) = h;
        *(f16x8*)(sA[1] + off) = lo;
    }
    __syncthreads();

    float4 pf0, pf1, pf2, pf3;
    const char* Ub = (const char*)U16 + (size_t)bid * 64 * 256;

    #define STAGE(r) {                                                          \
        const char* gp = Ub + (size_t)(r) * 32768 * 256;                        \
        pf0 = *(const float4*)(gp + (0 * 256 + tid) * 16);                      \
        pf1 = *(const float4*)(gp + (1 * 256 + tid) * 16);                      \
        pf2 = *(const float4*)(gp + (2 * 256 + tid) * 16);                      \
        pf3 = *(const float4*)(gp + (3 * 256 + tid) * 16);                      \
    }
    #define WRITE(buf) {                                                        \
        _Pragma("unroll")                                                       \
        for (int i = 0; i < 4; i++) {                                           \
            int c = i * 256 + tid;                                              \
            int row = c >> 4, cc = c & 15;                                      \
            int off = row * 256 + ((cc * 16) ^ ((row & 7) << 4));               \
            *(float4*)(sA[buf] + off) = (i==0)?pf0:(i==1)?pf1:(i==2)?pf2:pf3;   \
        }                                                                       \
    }

    // ---- self superblock (3-term), U0 prefetch in flight ----
    STAGE(0);
    {
        const ushort* Wb = Wfrag + (size_t)(8 * 2) * 16384;
        #pragma unroll
        for (int ks = 0; ks < 4; ks++) {
            int kb = ks * 64 + kq * 16;
            f16x8 ah[4], al[4], bh[2], bl[2];
            #pragma unroll
            for (int nf = 0; nf < 2; nf++) {
                size_t bo = (size_t)(((nfg0 + nf) * 4 + ks) * 64 + l) * 8;
                bh[nf] = *(const f16x8*)(Wb + bo);
                bl[nf] = *(const f16x8*)(Wb + 16384 + bo);
            }
            #pragma unroll
            for (int mf = 0; mf < 4; mf++) {
                int row = mf * 16 + lr;
                int off = row * 256 + (kb ^ ((row & 7) << 4));
                ah[mf] = *(const f16x8*)(sA[0] + off);
                al[mf] = *(const f16x8*)(sA[1] + off);
            }
            #pragma unroll
            for (int mf = 0; mf < 4; mf++)
                #pragma unroll
                for (int nf = 0; nf < 2; nf++) {
                    acc[mf][nf] = __builtin_amdgcn_mfma_f32_16x16x32_f16(ah[mf], bh[nf], acc[mf][nf], 0, 0, 0);
                    acc[mf][nf] = __builtin_amdgcn_mfma_f32_16x16x32_f16(ah[mf], bl[nf], acc[mf][nf], 0, 0, 0);
                    acc[mf][nf] = __builtin_amdgcn_mfma_f32_16x16x32_f16(al[mf], bh[nf], acc[mf][nf], 0, 0, 0);
                }
        }
    }
    WRITE(2);                                     // U0 -> buf2 = (0+2)%3 (untouched, no race)
    __syncthreads();

    // ---- 8 U superblocks, one sync each: STAGE(r+1) | MFMA(r) | WRITE(U_{r+1} -> r%3) | sync ----
    for (int r = 0; r < RR; r++) {
        if (r < 7) STAGE(r + 1);
        const ushort* Wb = Wfrag + (size_t)(r * 2) * 16384;
        const char* bufp = sA[(r + 2) % 3];
        #pragma unroll
        for (int ks = 0; ks < 4; ks++) {
            int kb = ks * 64 + kq * 16;
            f16x8 av[4], bh[2], bl[2];
            #pragma unroll
            for (int nf = 0; nf < 2; nf++) {
                size_t bo = (size_t)(((nfg0 + nf) * 4 + ks) * 64 + l) * 8;
                bh[nf] = *(const f16x8*)(Wb + bo);
                bl[nf] = *(const f16x8*)(Wb + 16384 + bo);
            }
            #pragma unroll
            for (int mf = 0; mf < 4; mf++) {
                int row = mf * 16 + lr;
                av[mf] = *(const f16x8*)(bufp + row * 256 + (kb ^ ((row & 7) << 4)));
            }
            #pragma unroll
            for (int mf = 0; mf < 4; mf++)
                #pragma unroll
                for (int nf = 0; nf < 2; nf++) {
                    acc[mf][nf] = __builtin_amdgcn_mfma_f32_16x16x32_f16(av[mf], bh[nf], acc[mf][nf], 0, 0, 0);
                    acc[mf][nf] = __builtin_amdgcn_mfma_f32_16x16x32_f16(av[mf], bl[nf], acc[mf][nf], 0, 0, 0);
                }
        }
        if (r < 7) {
            WRITE(r % 3);                         // U_{r+1} -> buf (r+3)%3; last readers at r-2, behind sync r-1
            __syncthreads();
        }
    }

    // ---- epilogue: sigmoid + store (D: col=lane&15, row=(lane>>4)*4+j) ----
    #pragma unroll
    for (int mf = 0; mf < 4; mf++)
        #pragma unroll
        for (int j = 0; j < 4; j++) {
            int lrow = mf * 16 + kq * 4 + j;
            size_t slot = (size_t)bid * 64 + lrow;
            #pragma unroll
            for (int nf = 0; nf < 2; nf++) {
                int col = (nfg0 + nf) * 16 + lr;
                float x = acc[mf][nf][j];
                out[slot * 128 + col] = 1.f / (1.f + __expf(-x));
            }
        }
    #undef STAGE
    #undef WRITE
}

extern "C" void kernel_launch(void* const* d_in, const int* in_sizes, int n_in,
                              void* d_out, int out_size, void* d_ws, size_t ws_size,
                              hipStream_t stream)
{
    const float* embeddings = (const float*)d_in[0];
    const int*   head_idx   = (const int*)d_in[1];
    const float* head_e     = (const float*)d_in[2];
    const int*   tail_idx   = (const int*)d_in[3];
    const float* tail_e     = (const float*)d_in[4];
    const int*   adj_rows   = (const int*)d_in[5];
    const int*   adj_cols   = (const int*)d_in[6];
    const float* adj_vals   = (const float*)d_in[7];
    const float* rel_k      = (const float*)d_in[8];
    const float* self_k     = (const float*)d_in[9];
    float* out = (float*)d_out;

    // workspace layout (~90 MB)
    char* ws = (char*)d_ws;
    uint*   head  = (uint*)ws;                        //  3,200,000 B (uint2 per (n,r))
    ushort* Wfrag = (ushort*)(ws + 3200000);          //    589,824 B
    ushort* emb16 = (ushort*)(ws + 3790336);          // 12,800,000 B
    uint2*  epack = (uint2*)(ws + 16590336);          //  6,400,000 B
    ushort* U16   = (ushort*)(ws + 22990336);         // 67,108,864 B

    hipMemsetAsync(head, 0xFF, (size_t)NN * 8 * 2 * 4, stream);

    prep<<<800, 256, 0, stream>>>(embeddings, rel_k, self_k,
                                  adj_rows, adj_cols, adj_vals,
                                  head, epack, emb16, Wfrag);

    gatherU<<<16384, 256, 0, stream>>>(head_idx, tail_idx, head, epack, emb16, U16);

    gemm<<<512, 256, 0, stream>>>(head_e, tail_e, U16, Wfrag, out);
}

// Round 9
// 97.874 us; speedup vs baseline: 1.4302x; 1.2398x over previous
//
#include <hip/hip_runtime.h>
#include <math.h>

#define NN 50000
#define RR 8
#define EE 100000
#define BB 16384
#define ET 800000
#define NB 98                 // coarse buckets per relation (512 nodes each)
#define CAP 2048              // region stride in edges (stored deg <= 2047)
#define OVFCAP 1024

typedef unsigned int uint;
typedef unsigned short ushort;
typedef __attribute__((ext_vector_type(4))) float f32x4;
typedef _Float16 f16x8 __attribute__((ext_vector_type(8)));

// pay4[pos]: (col<<16 | val_fp16), grouped by (r, node) per CSR.
// csr[r*NN+n] = (absStart << 11) | deg   (absStart < 784*2048+2047 < 2^21, deg <= 2047)
// U16: 8 planes of [32768 slots][128] fp16. Wfrag: [slot(9)][hi/lo][nfg(8)][ks(4)][lane(64)][8 f16]

// ========== scatterK: coarse partition (LDS hist, 39K global atomics) + emb16 + Wfrag ==========
// grid 800: 0..399 partition 2000 edges each (block fully inside one relation);
//           400..790 emb16; 791..799 Wfrag.
__global__ __launch_bounds__(256) void scatterK(
    const float* __restrict__ emb, const float* __restrict__ rel_k, const float* __restrict__ self_k,
    const int* __restrict__ adj_rows, const int* __restrict__ adj_cols, const float* __restrict__ adj_vals,
    uint* __restrict__ cursor, uint* __restrict__ ovfcnt, uint* __restrict__ ovflist,
    uint2* __restrict__ gpart, ushort* __restrict__ emb16, ushort* __restrict__ Wfrag)
{
    __shared__ int  srow[2000];
    __shared__ int  hist[NB];
    __shared__ uint lbase[NB];
    const int tid = threadIdx.x, bid = blockIdx.x;

    if (bid < 400) {
        const int r  = bid / 50;             // 50 blocks x 2000 edges = 100000 per relation
        const int e0 = bid * 2000;
        for (int k = tid; k < NB; k += 256) hist[k] = 0;
        __syncthreads();
        for (int i = tid; i < 2000; i += 256) {
            int n = adj_rows[e0 + i];
            srow[i] = n;
            atomicAdd(&hist[n >> 9], 1);
        }
        __syncthreads();
        if (tid < NB) {                       // ONE global atomic per (block,bucket)
            int h = hist[tid];
            lbase[tid] = h ? atomicAdd(&cursor[r * NB + tid], (uint)h) : 0u;
        }
        __syncthreads();
        for (int i = tid; i < 2000; i += 256) {
            int n = srow[i];
            int c = n >> 9;
            uint prel = atomicAdd(&lbase[c], 1u);       // LDS rank
            int e = e0 + i;
            ushort v16 = __builtin_bit_cast(ushort, (_Float16)adj_vals[e]);
            uint pay = ((uint)adj_cols[e] << 16) | (uint)v16;
            if (prel < (uint)(CAP - 1)) {
                gpart[(size_t)(r * NB + c) * CAP + prel] = make_uint2(pay, (uint)n);
            } else {                                    // insurance; P ~ 0
                uint o = atomicAdd(ovfcnt, 1u);
                if (o < OVFCAP) ovflist[o] = (uint)e;
            }
        }
    } else if (bid < 791) {
        // ---- emb -> fp16, rows [(bid-400)*128, +128) ----
        int b = bid - 400;
        #pragma unroll
        for (int i = 0; i < 16; i++) {
            int c = i * 256 + tid;
            int row = b * 128 + (c >> 5);
            if (row < NN) {
                int k4 = (c & 31) * 4;
                float4 v = *(const float4*)(emb + (size_t)row * 128 + k4);
                _Float16 h4[4] = {(_Float16)v.x, (_Float16)v.y, (_Float16)v.z, (_Float16)v.w};
                *(ulonglong1*)(emb16 + (size_t)row * 128 + k4) = *(ulonglong1*)h4;
            }
        }
    } else {
        // ---- W prepack (hi/lo fragment layout), LDS-free (verbatim round 8) ----
        int r = bid - 791;                    // 0..8 (8 = self)
        const float* src = (r < RR) ? rel_k + (size_t)r * 128 * 128 : self_k;
        #pragma unroll
        for (int q = 0; q < 8; q++) {
            int ls = q * 256 + tid;
            int nfg = ls >> 8, ks = (ls >> 6) & 3, lane = ls & 63;
            int n = nfg * 16 + (lane & 15);
            int k0 = ks * 32 + (lane >> 4) * 8;
            f16x8 hi, lo;
            #pragma unroll
            for (int j = 0; j < 8; j++) {
                float x = src[(size_t)(k0 + j) * 128 + n];
                _Float16 h = (_Float16)x;
                hi[j] = h;
                lo[j] = (_Float16)(x - (float)h);
            }
            size_t bo = (size_t)(r * 2) * 16384 + (size_t)(nfg * 4 + ks) * 512 + (size_t)lane * 8;
            *(f16x8*)(Wfrag + bo)         = hi;
            *(f16x8*)(Wfrag + 16384 + bo) = lo;
        }
    }
}

// ========== groupK: LDS counting-sort per coarse bucket -> packed CSR + 4B payloads ==========
// grid 784 = 8 relations x 98 buckets.
__global__ __launch_bounds__(256) void groupK(
    const uint* __restrict__ cursor, const uint2* __restrict__ gpart,
    uint* __restrict__ pay4, uint* __restrict__ csr)
{
    __shared__ ushort skey[CAP];
    __shared__ uint   spin[CAP];
    __shared__ uint   ssort[CAP];
    __shared__ int    cnt2[512];
    __shared__ int    sa[512], sb[512];
    __shared__ int    cur2[512];
    const int tid = threadIdx.x, rc = blockIdx.x;
    const int c = rc % NB, r = rc / NB;
    const int nodes0 = c * 512;
    const int nnodes = (c == NB - 1) ? (NN - nodes0) : 512;   // 336 for c=97
    uint cntv = cursor[rc]; if (cntv > (uint)(CAP - 1)) cntv = CAP - 1;
    const int cnt = (int)cntv;

    for (int k = tid; k < 512; k += 256) cnt2[k] = 0;
    __syncthreads();
    for (int i = tid; i < cnt; i += 256) {
        uint2 p = gpart[(size_t)rc * CAP + i];
        int key = (int)p.y - nodes0;          // in [0, nnodes)
        skey[i] = (ushort)key;
        spin[i] = p.x;
        atomicAdd(&cnt2[key], 1);
    }
    __syncthreads();
    // inclusive scan of cnt2 -> src (double-buffered Hillis-Steele, 512 wide)
    for (int k = tid; k < 512; k += 256) sa[k] = cnt2[k];
    __syncthreads();
    int* src = sa; int* dst = sb;
    for (int d = 1; d < 512; d <<= 1) {
        for (int k = tid; k < 512; k += 256)
            dst[k] = src[k] + (k >= d ? src[k - d] : 0);
        __syncthreads();
        int* t = src; src = dst; dst = t;
    }
    for (int k = tid; k < 512; k += 256) cur2[k] = k ? src[k - 1] : 0;   // exclusive
    __syncthreads();
    for (int i = tid; i < cnt; i += 256) {
        int p = atomicAdd(&cur2[skey[i]], 1);
        ssort[p] = spin[i];
    }
    __syncthreads();
    for (int i = tid; i < cnt; i += 256)
        pay4[(size_t)rc * CAP + i] = ssort[i];
    for (int j = tid; j < nnodes; j += 256) {
        uint start = (uint)rc * CAP + (uint)(j ? src[j - 1] : 0);
        csr[r * NN + nodes0 + j] = (start << 11) | (uint)cnt2[j];
    }
}

// ========== gatherU v3: CSR ranges, contiguous payload, no pointer chase ==========
// grid 16384 x 256: bid>>11 = r; 16-lane group per slot.
__global__ __launch_bounds__(256, 8) void gatherU(
    const int* __restrict__ head_idx, const int* __restrict__ tail_idx,
    const uint* __restrict__ csr, const uint* __restrict__ pay4,
    const int* __restrict__ adj_rows, const int* __restrict__ adj_cols, const float* __restrict__ adj_vals,
    const uint* __restrict__ ovfcnt, const uint* __restrict__ ovflist,
    const ushort* __restrict__ emb16, ushort* __restrict__ U16)
{
    const int tid = threadIdx.x, bid = blockIdx.x;
    const int g16 = tid >> 4, l16 = tid & 15;
    const int r = bid >> 11;
    const int slot = (bid & 2047) * 16 + g16;
    int n = (slot < BB) ? head_idx[slot] : tail_idx[slot - BB];
    uint cd = csr[r * NN + n];
    uint s = cd >> 11;
    int deg = (int)(cd & 2047u);
    float a[8] = {0.f,0.f,0.f,0.f,0.f,0.f,0.f,0.f};
    for (int i = 0; i < deg; i++) {
        uint p = pay4[s + i];                 // contiguous; independent of emb load below
        float v = (float)__builtin_bit_cast(_Float16, (ushort)(p & 0xFFFFu));
        f16x8 em = *(const f16x8*)(emb16 + (size_t)(p >> 16) * 128 + l16 * 8);
        #pragma unroll
        for (int q = 0; q < 8; q++) a[q] = fmaf(v, (float)em[q], a[q]);
    }
    // overflow insurance (novf == 0 in practice; one broadcast 4B read)
    uint novf = *ovfcnt; if (novf > OVFCAP) novf = OVFCAP;
    for (uint o = 0; o < novf; o++) {
        uint e = ovflist[o];
        int re = (int)(e / EE);
        if (re == r && adj_rows[e] == n) {
            float v = adj_vals[e];
            f16x8 em = *(const f16x8*)(emb16 + (size_t)adj_cols[e] * 128 + l16 * 8);
            #pragma unroll
            for (int q = 0; q < 8; q++) a[q] = fmaf(v, (float)em[q], a[q]);
        }
    }
    f16x8 uu;
    #pragma unroll
    for (int q = 0; q < 8; q++) uu[q] = (_Float16)a[q];
    *(f16x8*)(U16 + ((size_t)r * 32768 + slot) * 128 + l16 * 8) = uu;
}

// =================== gemm: verbatim round 8 (passing) ===================
__global__ __launch_bounds__(256) void gemm(
    const float* __restrict__ head_e, const float* __restrict__ tail_e,
    const ushort* __restrict__ U16, const ushort* __restrict__ Wfrag,
    float* __restrict__ out)
{
    __shared__ char sA[3][16384];
    const int tid = threadIdx.x, bid = blockIdx.x;
    const int w = tid >> 6, l = tid & 63;
    const int lr = l & 15, kq = l >> 4;
    const int nfg0 = w * 2;

    f32x4 acc[4][2];
    #pragma unroll
    for (int a = 0; a < 4; a++)
        #pragma unroll
        for (int b = 0; b < 2; b++) acc[a][b] = (f32x4){0.f, 0.f, 0.f, 0.f};

    const float* S = (bid < 256) ? head_e + (size_t)bid * 64 * 128
                                 : tail_e + (size_t)(bid - 256) * 64 * 128;
    #pragma unroll
    for (int i = 0; i < 4; i++) {
        int c = i * 256 + tid;
        int row = c >> 4;
        int k8 = (c & 15) * 8;
        float4 v0 = *(const float4*)(S + (size_t)row * 128 + k8);
        float4 v1 = *(const float4*)(S + (size_t)row * 128 + k8 + 4);
        float xs[8] = {v0.x, v0.y, v0.z, v0.w, v1.x, v1.y, v1.z, v1.w};
        f16x8 h, lo;
        #pragma unroll
        for (int j = 0; j < 8; j++) {
            _Float16 hh = (_Float16)xs[j];
            h[j] = hh;
            lo[j] = (_Float16)(xs[j] - (float)hh);
        }
        int off = row * 256 + ((k8 * 2) ^ ((row & 7) << 4));
        *(f16x8*)(sA[0] + off) = h;
        *(f16x8*)(sA[1] + off) = lo;
    }
    __syncthreads();

    float4 pf0, pf1, pf2, pf3;
    const char* Ub = (const char*)U16 + (size_t)bid * 64 * 256;

    #define STAGE(r) {                                                          \
        const char* gp = Ub + (size_t)(r) * 32768 * 256;                        \
        pf0 = *(const float4*)(gp + (0 * 256 + tid) * 16);                      \
        pf1 = *(const float4*)(gp + (1 * 256 + tid) * 16);                      \
        pf2 = *(const float4*)(gp + (2 * 256 + tid) * 16);                      \
        pf3 = *(const float4*)(gp + (3 * 256 + tid) * 16);                      \
    }
    #define WRITE(buf) {                                                        \
        _Pragma("unroll")                                                       \
        for (int i = 0; i < 4; i++) {                                           \
            int c = i * 256 + tid;                                              \
            int row = c >> 4, cc = c & 15;                                      \
            int off = row * 256 + ((cc * 16) ^ ((row & 7) << 4));               \
            *(float4*)(sA[buf] + off) = (i==0)?pf0:(i==1)?pf1:(i==2)?pf2:pf3;   \
        }                                                                       \
    }

    STAGE(0);
    {
        const ushort* Wb = Wfrag + (size_t)(8 * 2) * 16384;
        #pragma unroll
        for (int ks = 0; ks < 4; ks++) {
            int kb = ks * 64 + kq * 16;
            f16x8 ah[4], al[4], bh[2], bl[2];
            #pragma unroll
            for (int nf = 0; nf < 2; nf++) {
                size_t bo = (size_t)(((nfg0 + nf) * 4 + ks) * 64 + l) * 8;
                bh[nf] = *(const f16x8*)(Wb + bo);
                bl[nf] = *(const f16x8*)(Wb + 16384 + bo);
            }
            #pragma unroll
            for (int mf = 0; mf < 4; mf++) {
                int row = mf * 16 + lr;
                int off = row * 256 + (kb ^ ((row & 7) << 4));
                ah[mf] = *(const f16x8*)(sA[0] + off);
                al[mf] = *(const f16x8*)(sA[1] + off);
            }
            #pragma unroll
            for (int mf = 0; mf < 4; mf++)
                #pragma unroll
                for (int nf = 0; nf < 2; nf++) {
                    acc[mf][nf] = __builtin_amdgcn_mfma_f32_16x16x32_f16(ah[mf], bh[nf], acc[mf][nf], 0, 0, 0);
                    acc[mf][nf] = __builtin_amdgcn_mfma_f32_16x16x32_f16(ah[mf], bl[nf], acc[mf][nf], 0, 0, 0);
                    acc[mf][nf] = __builtin_amdgcn_mfma_f32_16x16x32_f16(al[mf], bh[nf], acc[mf][nf], 0, 0, 0);
                }
        }
    }
    WRITE(2);
    __syncthreads();

    for (int r = 0; r < RR; r++) {
        if (r < 7) STAGE(r + 1);
        const ushort* Wb = Wfrag + (size_t)(r * 2) * 16384;
        const char* bufp = sA[(r + 2) % 3];
        #pragma unroll
        for (int ks = 0; ks < 4; ks++) {
            int kb = ks * 64 + kq * 16;
            f16x8 av[4], bh[2], bl[2];
            #pragma unroll
            for (int nf = 0; nf < 2; nf++) {
                size_t bo = (size_t)(((nfg0 + nf) * 4 + ks) * 64 + l) * 8;
                bh[nf] = *(const f16x8*)(Wb + bo);
                bl[nf] = *(const f16x8*)(Wb + 16384 + bo);
            }
            #pragma unroll
            for (int mf = 0; mf < 4; mf++) {
                int row = mf * 16 + lr;
                av[mf] = *(const f16x8*)(bufp + row * 256 + (kb ^ ((row & 7) << 4)));
            }
            #pragma unroll
            for (int mf = 0; mf < 4; mf++)
                #pragma unroll
                for (int nf = 0; nf < 2; nf++) {
                    acc[mf][nf] = __builtin_amdgcn_mfma_f32_16x16x32_f16(av[mf], bh[nf], acc[mf][nf], 0, 0, 0);
                    acc[mf][nf] = __builtin_amdgcn_mfma_f32_16x16x32_f16(av[mf], bl[nf], acc[mf][nf], 0, 0, 0);
                }
        }
        if (r < 7) {
            WRITE(r % 3);
            __syncthreads();
        }
    }

    #pragma unroll
    for (int mf = 0; mf < 4; mf++)
        #pragma unroll
        for (int j = 0; j < 4; j++) {
            int lrow = mf * 16 + kq * 4 + j;
            size_t slot = (size_t)bid * 64 + lrow;
            #pragma unroll
            for (int nf = 0; nf < 2; nf++) {
                int col = (nfg0 + nf) * 16 + lr;
                float x = acc[mf][nf][j];
                out[slot * 128 + col] = 1.f / (1.f + __expf(-x));
            }
        }
    #undef STAGE
    #undef WRITE
}

extern "C" void kernel_launch(void* const* d_in, const int* in_sizes, int n_in,
                              void* d_out, int out_size, void* d_ws, size_t ws_size,
                              hipStream_t stream)
{
    const float* embeddings = (const float*)d_in[0];
    const int*   head_idx   = (const int*)d_in[1];
    const float* head_e     = (const float*)d_in[2];
    const int*   tail_idx   = (const int*)d_in[3];
    const float* tail_e     = (const float*)d_in[4];
    const int*   adj_rows   = (const int*)d_in[5];
    const int*   adj_cols   = (const int*)d_in[6];
    const float* adj_vals   = (const float*)d_in[7];
    const float* rel_k      = (const float*)d_in[8];
    const float* self_k     = (const float*)d_in[9];
    float* out = (float*)d_out;

    // workspace layout (~101.4 MB)
    char* ws = (char*)d_ws;
    uint*   cursor  = (uint*)ws;                      //   3,136 B (784)
    uint*   ovfcnt  = (uint*)(ws + 3136);             //       4 B
    uint*   ovflist = (uint*)(ws + 3140);             //   4,096 B
    ushort* Wfrag   = (ushort*)(ws + 8192);           //     589,824 B
    ushort* emb16   = (ushort*)(ws + 598016);         //  12,800,000 B
    uint*   csr     = (uint*)(ws + 13398016);         //   1,600,000 B
    uint*   pay4    = (uint*)(ws + 14998016);         //   6,422,528 B
    uint2*  gpart   = (uint2*)(ws + 21420544);        //  12,845,056 B
    ushort* U16     = (ushort*)(ws + 34265600);       //  67,108,864 B

    hipMemsetAsync(cursor, 0, 3140, stream);          // cursor + ovfcnt

    scatterK<<<800, 256, 0, stream>>>(embeddings, rel_k, self_k,
                                      adj_rows, adj_cols, adj_vals,
                                      cursor, ovfcnt, ovflist, gpart, emb16, Wfrag);

    groupK<<<784, 256, 0, stream>>>(cursor, gpart, pay4, csr);

    gatherU<<<16384, 256, 0, stream>>>(head_idx, tail_idx, csr, pay4,
                                       adj_rows, adj_cols, adj_vals,
                                       ovfcnt, ovflist, emb16, U16);

    gemm<<<512, 256, 0, stream>>>(head_e, tail_e, U16, Wfrag, out);
}